// Round 1
// baseline (136.449 us; speedup 1.0000x reference)
//
#include <hip/hip_runtime.h>
#include <stdint.h>
#include <stddef.h>

typedef __bf16 bf16_t;
typedef __bf16 bf16x8 __attribute__((ext_vector_type(8)));
typedef float  f32x4  __attribute__((ext_vector_type(4)));

#define NIMG 16
#define CIN  128
#define COUT 128
#define HH   56
#define WW   56
#define PR   58      // padded rows (1 + 56 + 1)
#define PCOL 66      // padded cols (1 + 56 + 1 + 8 slack for the 64-wide sp tile)
#define CI_STRIDE 40 // LDS ci stride (32 used + 8 pad; 80B = 16B-aligned, banks 2-way max)
#define ROWPAIRS 28

// ---------- prologue 1: W[co][ci][kh][kw] fp32 -> Wt[khkw][co][ci] bf16 ----------
__global__ void wtrans_kernel(const float* __restrict__ w, bf16_t* __restrict__ wt) {
    int idx  = blockIdx.x * 256 + threadIdx.x;   // exactly 147456 threads
    int khkw = idx >> 14;                        // / (128*128)
    int rem  = idx & 16383;
    int co   = rem >> 7;
    int ci   = rem & 127;
    wt[idx] = (bf16_t)w[(co * CIN + ci) * 9 + khkw];
}

// ---------- prologue 2: in[n][ci][h][w] fp32 -> P[n][r][c][ci] bf16, zero borders ----------
__global__ void itrans_kernel(const float* __restrict__ in, bf16_t* __restrict__ P) {
    __shared__ float t[CIN][WW + 1];             // +1 pad: conflict-free transposed reads
    int b = blockIdx.x;                           // 16*58 blocks: one padded row each
    int n = b / PR, r = b % PR;
    int tid = threadIdx.x;
    bf16_t* dst = P + ((size_t)n * PR + r) * (PCOL * CIN);
    if (r >= 1 && r <= HH) {
        const float* src = in + (size_t)n * CIN * HH * WW + (size_t)(r - 1) * WW;
        for (int idx = tid; idx < CIN * WW; idx += 256) {
            int ci = idx / WW, w = idx - ci * WW;
            t[ci][w] = src[(size_t)ci * (HH * WW) + w];
        }
        __syncthreads();
        for (int idx = tid; idx < PCOL * CIN; idx += 256) {
            int c = idx >> 7, ci = idx & 127;
            float v = (c >= 1 && c <= WW) ? t[ci][c - 1] : 0.f;
            dst[idx] = (bf16_t)v;
        }
    } else {
        for (int idx = tid; idx < PCOL * CIN; idx += 256) dst[idx] = (bf16_t)0.f;
    }
}

// ---------- main: implicit GEMM, block = (n, 2 output rows) x all 128 co ----------
// wave (ws,wc): ws = which output row, wc = which co half; wave tile 64sp x 64co.
__global__ __launch_bounds__(256, 2)
void conv_mfma_kernel(const bf16_t* __restrict__ P, const bf16_t* __restrict__ Wt,
                      const float* __restrict__ bias, float* __restrict__ out) {
    __shared__ bf16_t lds[2][4 * PCOL * CI_STRIDE];   // 2 x 21120B double buffer

    const int bx = blockIdx.x;
    const int n  = bx / ROWPAIRS;
    const int rp = bx % ROWPAIRS;
    const int h0 = rp * 2;

    const int tid  = threadIdx.x;
    const int lane = tid & 63;
    const int wave = tid >> 6;
    const int ws  = wave & 1;
    const int wc  = wave >> 1;
    const int l15 = lane & 15;
    const int l4  = lane >> 4;

    // padded input rows h0 .. h0+3 feed output rows h0, h0+1
    const bf16_t* Pb = P + ((size_t)n * PR + h0) * (PCOL * CIN);

    f32x4 acc[4][4];   // [co tile][sp tile]
#pragma unroll
    for (int a = 0; a < 4; ++a)
#pragma unroll
        for (int b2 = 0; b2 < 4; ++b2) acc[a][b2] = (f32x4){0.f, 0.f, 0.f, 0.f};

    uint4 stg[5];      // staging regs: 4r x 66c x 32ci bf16 = 1056 x 16B groups

    // ---- stage chunk 0 (ci 0..31)
#pragma unroll
    for (int it = 0; it < 5; ++it) {
        int G = it * 256 + tid;
        if (G < 1056) {
            int g = G & 3, rc = G >> 2;           // rc = r*66 + c (contiguous in P)
            stg[it] = *(const uint4*)(Pb + (size_t)rc * CIN + g * 8);
        }
    }
#pragma unroll
    for (int it = 0; it < 5; ++it) {
        int G = it * 256 + tid;
        if (G < 1056) {
            int g = G & 3, rc = G >> 2;
            *(uint4*)&lds[0][rc * CI_STRIDE + g * 8] = stg[it];
        }
    }
    __syncthreads();

    const bf16_t* wpbase = Wt + (size_t)(wc * 64 + l15) * CIN + l4 * 8;

    for (int chunk = 0; chunk < 4; ++chunk) {
        // prefetch next ci-chunk into regs (global loads fly during compute)
        if (chunk < 3) {
            int ci0 = (chunk + 1) * 32;
#pragma unroll
            for (int it = 0; it < 5; ++it) {
                int G = it * 256 + tid;
                if (G < 1056) {
                    int g = G & 3, rc = G >> 2;
                    stg[it] = *(const uint4*)(Pb + (size_t)rc * CIN + ci0 + g * 8);
                }
            }
        }

        const bf16_t* lb = lds[chunk & 1];
        const bf16_t* wp = wpbase + chunk * 32;
#pragma unroll
        for (int khkw = 0; khkw < 9; ++khkw) {
            const int kh = khkw / 3, kw = khkw % 3;
            bf16x8 af[4];
#pragma unroll
            for (int tc = 0; tc < 4; ++tc)
                af[tc] = *(const bf16x8*)(wp + (size_t)khkw * (COUT * CIN) + tc * 16 * CIN);
            const int r = ws + kh;
#pragma unroll
            for (int ts = 0; ts < 4; ++ts) {
                int c = ts * 16 + l15 + kw;      // < 66 always
                bf16x8 bfm = *(const bf16x8*)(lb + (r * PCOL + c) * CI_STRIDE + l4 * 8);
#pragma unroll
                for (int tc = 0; tc < 4; ++tc)
                    acc[tc][ts] = __builtin_amdgcn_mfma_f32_16x16x32_bf16(
                        af[tc], bfm, acc[tc][ts], 0, 0, 0);
            }
        }

        // write prefetched chunk to the other buffer; prior readers of that buffer
        // finished before the previous iteration's barrier.
        if (chunk < 3) {
#pragma unroll
            for (int it = 0; it < 5; ++it) {
                int G = it * 256 + tid;
                if (G < 1056) {
                    int g = G & 3, rc = G >> 2;
                    *(uint4*)&lds[(chunk + 1) & 1][rc * CI_STRIDE + g * 8] = stg[it];
                }
            }
        }
        __syncthreads();
    }

    // ---- epilogue: D[co][sp], col = lane&15 (w), row = (lane>>4)*4 + i (co)
    const int h   = h0 + ws;
    const int co0 = wc * 64;
    float bv[4][4];
#pragma unroll
    for (int tc = 0; tc < 4; ++tc)
#pragma unroll
        for (int i = 0; i < 4; ++i)
            bv[tc][i] = bias[co0 + tc * 16 + l4 * 4 + i];

#pragma unroll
    for (int tc = 0; tc < 4; ++tc) {
#pragma unroll
        for (int ts = 0; ts < 4; ++ts) {
            int w0 = ts * 16 + l15;
            if (w0 < WW) {
#pragma unroll
                for (int i = 0; i < 4; ++i) {
                    int co = co0 + tc * 16 + l4 * 4 + i;
                    out[(((size_t)n * COUT + co) * HH + h) * WW + w0] = acc[tc][ts][i] + bv[tc][i];
                }
            }
        }
    }
}

extern "C" void kernel_launch(void* const* d_in, const int* in_sizes, int n_in,
                              void* d_out, int out_size, void* d_ws, size_t ws_size,
                              hipStream_t stream) {
    const float* in   = (const float*)d_in[0];
    const float* wgt  = (const float*)d_in[1];
    const float* bias = (const float*)d_in[2];
    float* out = (float*)d_out;

    bf16_t* P = (bf16_t*)d_ws;
    const size_t P_bytes = (size_t)NIMG * PR * PCOL * CIN * sizeof(bf16_t); // 15,679,488 (16B aligned)
    bf16_t* Wt = (bf16_t*)((char*)d_ws + P_bytes);                          // +294,912 B

    wtrans_kernel<<<576, 256, 0, stream>>>(wgt, Wt);
    itrans_kernel<<<NIMG * PR, 256, 0, stream>>>(in, P);
    conv_mfma_kernel<<<NIMG * ROWPAIRS, 256, 0, stream>>>(P, Wt, bias, out);
}